// Round 2
// baseline (782.508 us; speedup 1.0000x reference)
//
#include <hip/hip_runtime.h>

#define N_NODES 100000
#define N_EDGES 1600000
#define IN_F 128
#define HID_F 64
#define CLS_F 32

// --- degree ---------------------------------------------------------------
__global__ __launch_bounds__(256) void deg_init_kernel(float* __restrict__ deg) {
    int n = blockIdx.x * 256 + threadIdx.x;
    if (n < N_NODES) deg[n] = 1.0f;   // self-loop
}

__global__ __launch_bounds__(256) void deg_accum_kernel(const int* __restrict__ dst,
                                                        float* __restrict__ deg) {
    int e = blockIdx.x * 256 + threadIdx.x;
    if (e < N_EDGES) atomicAdd(&deg[dst[e]], 1.0f);
}

// --- layer 1: y1 = (x @ W1) * dinv ; agg1 = y1 (self-loop init) -----------
__global__ __launch_bounds__(256) void xw1_kernel(const float* __restrict__ x,
                                                  const float* __restrict__ W1,
                                                  const float* __restrict__ deg,
                                                  float* __restrict__ y1,
                                                  float* __restrict__ agg1) {
    __shared__ float Wl[IN_F * HID_F];   // 32 KB
    for (int i = threadIdx.x; i < IN_F * HID_F; i += 256) Wl[i] = W1[i];
    __syncthreads();

    int n = blockIdx.x * 256 + threadIdx.x;
    if (n >= N_NODES) return;

    float acc[HID_F];
#pragma unroll
    for (int j = 0; j < HID_F; j++) acc[j] = 0.f;

    const float4* xr = (const float4*)(x + (size_t)n * IN_F);
#pragma unroll
    for (int k0 = 0; k0 < IN_F; k0 += 4) {
        float4 x4 = xr[k0 / 4];
        float xv[4] = {x4.x, x4.y, x4.z, x4.w};
#pragma unroll
        for (int kk = 0; kk < 4; kk++) {
            float xk = xv[kk];
            const float* wrow = &Wl[(k0 + kk) * HID_F];
#pragma unroll
            for (int j = 0; j < HID_F; j++) acc[j] += xk * wrow[j];
        }
    }

    float dinv = rsqrtf(deg[n]);
    float* yo = y1 + (size_t)n * HID_F;
    float* ao = agg1 + (size_t)n * HID_F;
#pragma unroll
    for (int j = 0; j < HID_F; j += 4) {
        float4 v = make_float4(acc[j] * dinv, acc[j + 1] * dinv,
                               acc[j + 2] * dinv, acc[j + 3] * dinv);
        *(float4*)(yo + j) = v;
        *(float4*)(ao + j) = v;
    }
}

// --- scatter layer 1: agg1[dst] += y1[src], one lane per (edge,feature) ---
__global__ __launch_bounds__(256) void scatter1_kernel(const int* __restrict__ src,
                                                       const int* __restrict__ dst,
                                                       const float* __restrict__ y1,
                                                       float* __restrict__ agg1) {
    int gid = blockIdx.x * 256 + threadIdx.x;
    int e = gid >> 6;
    int f = gid & 63;
    if (e >= N_EDGES) return;
    int s = src[e], d = dst[e];
    atomicAdd(&agg1[(size_t)d * HID_F + f], y1[(size_t)s * HID_F + f]);
}

// --- layer 2 transform: h=relu(agg1*dinv+b1); y2=(h@W2)*dinv; agg2=y2 -----
__global__ __launch_bounds__(256) void layer2_kernel(const float* __restrict__ agg1,
                                                     const float* __restrict__ deg,
                                                     const float* __restrict__ W2,
                                                     const float* __restrict__ b1,
                                                     float* __restrict__ y2,
                                                     float* __restrict__ agg2) {
    __shared__ float Wl[HID_F * CLS_F];  // 8 KB
    __shared__ float bl[HID_F];
    for (int i = threadIdx.x; i < HID_F * CLS_F; i += 256) Wl[i] = W2[i];
    if (threadIdx.x < HID_F) bl[threadIdx.x] = b1[threadIdx.x];
    __syncthreads();

    int n = blockIdx.x * 256 + threadIdx.x;
    if (n >= N_NODES) return;

    float dinv = rsqrtf(deg[n]);
    float acc[CLS_F];
#pragma unroll
    for (int c = 0; c < CLS_F; c++) acc[c] = 0.f;

    const float4* ar = (const float4*)(agg1 + (size_t)n * HID_F);
#pragma unroll
    for (int j0 = 0; j0 < HID_F; j0 += 4) {
        float4 a4 = ar[j0 / 4];
        float hv[4] = {a4.x, a4.y, a4.z, a4.w};
#pragma unroll
        for (int jj = 0; jj < 4; jj++) {
            float h = fmaxf(hv[jj] * dinv + bl[j0 + jj], 0.f);
            const float* wrow = &Wl[(j0 + jj) * CLS_F];
#pragma unroll
            for (int c = 0; c < CLS_F; c++) acc[c] += h * wrow[c];
        }
    }

    float* yo = y2 + (size_t)n * CLS_F;
    float* ao = agg2 + (size_t)n * CLS_F;
#pragma unroll
    for (int c = 0; c < CLS_F; c += 4) {
        float4 v = make_float4(acc[c] * dinv, acc[c + 1] * dinv,
                               acc[c + 2] * dinv, acc[c + 3] * dinv);
        *(float4*)(yo + c) = v;
        *(float4*)(ao + c) = v;
    }
}

// --- scatter layer 2 ------------------------------------------------------
__global__ __launch_bounds__(256) void scatter2_kernel(const int* __restrict__ src,
                                                       const int* __restrict__ dst,
                                                       const float* __restrict__ y2,
                                                       float* __restrict__ agg2) {
    int gid = blockIdx.x * 256 + threadIdx.x;
    int e = gid >> 5;
    int f = gid & 31;
    if (e >= N_EDGES) return;
    int s = src[e], d = dst[e];
    atomicAdd(&agg2[(size_t)d * CLS_F + f], y2[(size_t)s * CLS_F + f]);
}

// --- epilogue: out = agg2*dinv + b2 ---------------------------------------
__global__ __launch_bounds__(256) void finish_kernel(const float* __restrict__ agg2,
                                                     const float* __restrict__ deg,
                                                     const float* __restrict__ b2,
                                                     float* __restrict__ out) {
    int gid = blockIdx.x * 256 + threadIdx.x;
    if (gid >= N_NODES * CLS_F) return;
    int n = gid >> 5;
    int c = gid & 31;
    float dinv = rsqrtf(deg[n]);
    out[gid] = agg2[gid] * dinv + b2[c];
}

extern "C" void kernel_launch(void* const* d_in, const int* in_sizes, int n_in,
                              void* d_out, int out_size, void* d_ws, size_t ws_size,
                              hipStream_t stream) {
    const float* x  = (const float*)d_in[0];
    const int*   ei = (const int*)d_in[1];
    // d_in[2] = edge_attr, unused by GCNConv
    const float* W1 = (const float*)d_in[3];
    const float* b1 = (const float*)d_in[4];
    const float* W2 = (const float*)d_in[5];
    const float* b2 = (const float*)d_in[6];
    float* out = (float*)d_out;

    const int* src = ei;
    const int* dst = ei + N_EDGES;

    // workspace layout (all f32):
    //   deg  : N                  (0.4 MB)
    //   y1   : N*64               (25.6 MB)   -- reused as y2 (N*32) + agg2 (N*32) for layer 2
    //   agg1 : N*64               (25.6 MB)
    char* ws = (char*)d_ws;
    float* deg  = (float*)ws;
    float* y1   = (float*)(ws + (((size_t)N_NODES * 4 + 255) / 256 * 256));
    float* agg1 = y1 + (size_t)N_NODES * HID_F;
    float* y2   = y1;                              // y1 dead after scatter1
    float* agg2 = y1 + (size_t)N_NODES * CLS_F;

    dim3 blk(256);
    deg_init_kernel<<<dim3((N_NODES + 255) / 256), blk, 0, stream>>>(deg);
    deg_accum_kernel<<<dim3((N_EDGES + 255) / 256), blk, 0, stream>>>(dst, deg);
    xw1_kernel<<<dim3((N_NODES + 255) / 256), blk, 0, stream>>>(x, W1, deg, y1, agg1);
    scatter1_kernel<<<dim3((N_EDGES * 64) / 256), blk, 0, stream>>>(src, dst, y1, agg1);
    layer2_kernel<<<dim3((N_NODES + 255) / 256), blk, 0, stream>>>(agg1, deg, W2, b1, y2, agg2);
    scatter2_kernel<<<dim3((N_EDGES * 32) / 256), blk, 0, stream>>>(src, dst, y2, agg2);
    finish_kernel<<<dim3((N_NODES * CLS_F + 255) / 256), blk, 0, stream>>>(agg2, deg, b2, out);
}

// Round 3
// 562.160 us; speedup vs baseline: 1.3920x; 1.3920x over previous
//
#include <hip/hip_runtime.h>

#define N_NODES 100000
#define N_EDGES 1600000
#define IN_F 128
#define HID_F 64
#define CLS_F 32

// ---------------------------------------------------------------------------
// CSR build: cnt (in-degree histogram) -> wave-scan segment alloc -> fill.
// Segment order across nodes is arbitrary (allocation by atomic ticket), which
// is fine: each node only reads its own [off, end) range.
// ---------------------------------------------------------------------------

__global__ __launch_bounds__(256) void init_kernel(int* __restrict__ cnt,
                                                   int* __restrict__ counter) {
    int n = blockIdx.x * 256 + threadIdx.x;
    if (n < N_NODES) cnt[n] = 0;
    if (n == 0) *counter = 0;
}

__global__ __launch_bounds__(256) void count_kernel(const int* __restrict__ dst,
                                                    int* __restrict__ cnt) {
    int e = blockIdx.x * 256 + threadIdx.x;
    if (e < N_EDGES) atomicAdd(&cnt[dst[e]], 1);
}

// off[n] = segment start, cursor[n] = running fill pointer (ends at off+cnt),
// dinv[n] = rsqrt(in_deg + 1)  (reference: deg from dst occurrences + self loop)
__global__ __launch_bounds__(256) void alloc_kernel(const int* __restrict__ cnt,
                                                    int* __restrict__ off,
                                                    int* __restrict__ cursor,
                                                    float* __restrict__ dinv,
                                                    int* __restrict__ counter) {
    int n = blockIdx.x * 256 + threadIdx.x;
    int lane = threadIdx.x & 63;
    int c = (n < N_NODES) ? cnt[n] : 0;
    if (n < N_NODES) dinv[n] = rsqrtf((float)(c + 1));
    // wave-inclusive scan of c
    int s = c;
#pragma unroll
    for (int d = 1; d < 64; d <<= 1) {
        int t = __shfl_up(s, d);
        if (lane >= d) s += t;
    }
    int total = __shfl(s, 63);
    int base = 0;
    if (lane == 63) base = atomicAdd(counter, total);
    base = __shfl(base, 63);
    if (n < N_NODES) {
        int o = base + s - c;   // exclusive prefix within wave + global base
        off[n] = o;
        cursor[n] = o;
    }
}

__global__ __launch_bounds__(256) void fill_kernel(const int* __restrict__ src,
                                                   const int* __restrict__ dst,
                                                   int* __restrict__ cursor,
                                                   int* __restrict__ csr) {
    int e = blockIdx.x * 256 + threadIdx.x;
    if (e >= N_EDGES) return;
    int p = atomicAdd(&cursor[dst[e]], 1);
    csr[p] = src[e];
}

// --- layer 1: y1 = (x @ W1) * dinv ----------------------------------------
__global__ __launch_bounds__(256) void xw1_kernel(const float* __restrict__ x,
                                                  const float* __restrict__ W1,
                                                  const float* __restrict__ dinv,
                                                  float* __restrict__ y1) {
    __shared__ float Wl[IN_F * HID_F];   // 32 KB
    for (int i = threadIdx.x; i < IN_F * HID_F; i += 256) Wl[i] = W1[i];
    __syncthreads();

    int n = blockIdx.x * 256 + threadIdx.x;
    if (n >= N_NODES) return;

    float acc[HID_F];
#pragma unroll
    for (int j = 0; j < HID_F; j++) acc[j] = 0.f;

    const float4* xr = (const float4*)(x + (size_t)n * IN_F);
#pragma unroll
    for (int k0 = 0; k0 < IN_F; k0 += 4) {
        float4 x4 = xr[k0 / 4];
        float xv[4] = {x4.x, x4.y, x4.z, x4.w};
#pragma unroll
        for (int kk = 0; kk < 4; kk++) {
            float xk = xv[kk];
            const float* wrow = &Wl[(k0 + kk) * HID_F];
#pragma unroll
            for (int j = 0; j < HID_F; j++) acc[j] += xk * wrow[j];
        }
    }

    float dv = dinv[n];
    float* yo = y1 + (size_t)n * HID_F;
#pragma unroll
    for (int j = 0; j < HID_F; j += 4) {
        *(float4*)(yo + j) = make_float4(acc[j] * dv, acc[j + 1] * dv,
                                         acc[j + 2] * dv, acc[j + 3] * dv);
    }
}

// --- gather layer 1: one wave per node, lane = feature --------------------
__global__ __launch_bounds__(256) void gather1_kernel(const int* __restrict__ off,
                                                      const int* __restrict__ endp,
                                                      const int* __restrict__ csr,
                                                      const float* __restrict__ y1,
                                                      float* __restrict__ agg1) {
    int node = (blockIdx.x * 256 + threadIdx.x) >> 6;
    int lane = threadIdx.x & 63;
    if (node >= N_NODES) return;
    int start = off[node], end = endp[node];

    float acc = y1[(size_t)node * HID_F + lane];   // self loop
    for (int j = start; j < end; j += 64) {
        int m = min(64, end - j);
        int nbr = (lane < m) ? csr[j + lane] : 0;
        int i = 0;
        for (; i + 4 <= m; i += 4) {
            int s0 = __shfl(nbr, i), s1 = __shfl(nbr, i + 1);
            int s2 = __shfl(nbr, i + 2), s3 = __shfl(nbr, i + 3);
            float v0 = y1[(size_t)s0 * HID_F + lane];
            float v1 = y1[(size_t)s1 * HID_F + lane];
            float v2 = y1[(size_t)s2 * HID_F + lane];
            float v3 = y1[(size_t)s3 * HID_F + lane];
            acc += (v0 + v1) + (v2 + v3);
        }
        for (; i < m; i++) {
            int s = __shfl(nbr, i);
            acc += y1[(size_t)s * HID_F + lane];
        }
    }
    agg1[(size_t)node * HID_F + lane] = acc;
}

// --- layer 2 transform: h=relu(agg1*dinv+b1); y2=(h@W2)*dinv --------------
__global__ __launch_bounds__(256) void layer2_kernel(const float* __restrict__ agg1,
                                                     const float* __restrict__ dinv,
                                                     const float* __restrict__ W2,
                                                     const float* __restrict__ b1,
                                                     float* __restrict__ y2) {
    __shared__ float Wl[HID_F * CLS_F];  // 8 KB
    __shared__ float bl[HID_F];
    for (int i = threadIdx.x; i < HID_F * CLS_F; i += 256) Wl[i] = W2[i];
    if (threadIdx.x < HID_F) bl[threadIdx.x] = b1[threadIdx.x];
    __syncthreads();

    int n = blockIdx.x * 256 + threadIdx.x;
    if (n >= N_NODES) return;

    float dv = dinv[n];
    float acc[CLS_F];
#pragma unroll
    for (int c = 0; c < CLS_F; c++) acc[c] = 0.f;

    const float4* ar = (const float4*)(agg1 + (size_t)n * HID_F);
#pragma unroll
    for (int j0 = 0; j0 < HID_F; j0 += 4) {
        float4 a4 = ar[j0 / 4];
        float hv[4] = {a4.x, a4.y, a4.z, a4.w};
#pragma unroll
        for (int jj = 0; jj < 4; jj++) {
            float h = fmaxf(hv[jj] * dv + bl[j0 + jj], 0.f);
            const float* wrow = &Wl[(j0 + jj) * CLS_F];
#pragma unroll
            for (int c = 0; c < CLS_F; c++) acc[c] += h * wrow[c];
        }
    }

    float* yo = y2 + (size_t)n * CLS_F;
#pragma unroll
    for (int c = 0; c < CLS_F; c += 4) {
        *(float4*)(yo + c) = make_float4(acc[c] * dv, acc[c + 1] * dv,
                                         acc[c + 2] * dv, acc[c + 3] * dv);
    }
}

// --- gather layer 2: half-wave (32 lanes) per node ------------------------
__global__ __launch_bounds__(256) void gather2_kernel(const int* __restrict__ off,
                                                      const int* __restrict__ endp,
                                                      const int* __restrict__ csr,
                                                      const float* __restrict__ y2,
                                                      float* __restrict__ agg2) {
    int node = (blockIdx.x * 256 + threadIdx.x) >> 5;
    int lane = threadIdx.x & 31;
    if (node >= N_NODES) return;
    int start = off[node], end = endp[node];

    float acc = y2[(size_t)node * CLS_F + lane];   // self loop
    for (int j = start; j < end; j += 32) {
        int m = min(32, end - j);
        int nbr = (lane < m) ? csr[j + lane] : 0;
        int i = 0;
        for (; i + 4 <= m; i += 4) {
            int s0 = __shfl(nbr, i, 32), s1 = __shfl(nbr, i + 1, 32);
            int s2 = __shfl(nbr, i + 2, 32), s3 = __shfl(nbr, i + 3, 32);
            float v0 = y2[(size_t)s0 * CLS_F + lane];
            float v1 = y2[(size_t)s1 * CLS_F + lane];
            float v2 = y2[(size_t)s2 * CLS_F + lane];
            float v3 = y2[(size_t)s3 * CLS_F + lane];
            acc += (v0 + v1) + (v2 + v3);
        }
        for (; i < m; i++) {
            int s = __shfl(nbr, i, 32);
            acc += y2[(size_t)s * CLS_F + lane];
        }
    }
    agg2[(size_t)node * CLS_F + lane] = acc;
}

// --- epilogue: out = agg2*dinv + b2 ---------------------------------------
__global__ __launch_bounds__(256) void finish_kernel(const float* __restrict__ agg2,
                                                     const float* __restrict__ dinv,
                                                     const float* __restrict__ b2,
                                                     float* __restrict__ out) {
    int gid = blockIdx.x * 256 + threadIdx.x;
    if (gid >= N_NODES * CLS_F) return;
    int n = gid >> 5;
    int c = gid & 31;
    out[gid] = agg2[gid] * dinv[n] + b2[c];
}

extern "C" void kernel_launch(void* const* d_in, const int* in_sizes, int n_in,
                              void* d_out, int out_size, void* d_ws, size_t ws_size,
                              hipStream_t stream) {
    const float* x  = (const float*)d_in[0];
    const int*   ei = (const int*)d_in[1];
    // d_in[2] = edge_attr, unused by GCNConv
    const float* W1 = (const float*)d_in[3];
    const float* b1 = (const float*)d_in[4];
    const float* W2 = (const float*)d_in[5];
    const float* b2 = (const float*)d_in[6];
    float* out = (float*)d_out;

    const int* src = ei;
    const int* dst = ei + N_EDGES;

    // workspace layout:
    //   dinv   : N f32          (0.4 MB)
    //   cnt    : N i32          (0.4 MB)
    //   off    : N i32          (0.4 MB)
    //   cursor : N i32          (0.4 MB)  -- after fill, cursor[n] == off[n]+cnt[n] == end
    //   counter: 64 i32 (pad)
    //   csr    : E i32          (6.4 MB)
    //   y1     : N*64 f32       (25.6 MB) -- reused as y2 (N*32) + agg2 (N*32)
    //   agg1   : N*64 f32       (25.6 MB)
    char* ws = (char*)d_ws;
    size_t npad = ((size_t)N_NODES * 4 + 255) / 256 * 256;
    float* dinv   = (float*)ws;
    int*   cnt    = (int*)(ws + npad);
    int*   off    = (int*)(ws + 2 * npad);
    int*   cursor = (int*)(ws + 3 * npad);
    int*   counter= (int*)(ws + 4 * npad);
    int*   csr    = (int*)(ws + 4 * npad + 256);
    float* y1     = (float*)(ws + 4 * npad + 256 + (size_t)N_EDGES * 4);
    float* agg1   = y1 + (size_t)N_NODES * HID_F;
    float* y2     = y1;                                // y1 dead after gather1
    float* agg2   = y1 + (size_t)N_NODES * CLS_F;

    dim3 blk(256);
    int nb_nodes = (N_NODES + 255) / 256;
    int nb_edges = (N_EDGES + 255) / 256;
    init_kernel <<<dim3(nb_nodes), blk, 0, stream>>>(cnt, counter);
    count_kernel<<<dim3(nb_edges), blk, 0, stream>>>(dst, cnt);
    alloc_kernel<<<dim3(nb_nodes), blk, 0, stream>>>(cnt, off, cursor, dinv, counter);
    fill_kernel <<<dim3(nb_edges), blk, 0, stream>>>(src, dst, cursor, csr);
    xw1_kernel  <<<dim3(nb_nodes), blk, 0, stream>>>(x, W1, dinv, y1);
    gather1_kernel<<<dim3((N_NODES * 64 + 255) / 256), blk, 0, stream>>>(off, cursor, csr, y1, agg1);
    layer2_kernel<<<dim3(nb_nodes), blk, 0, stream>>>(agg1, dinv, W2, b1, y2);
    gather2_kernel<<<dim3((N_NODES * 32 + 255) / 256), blk, 0, stream>>>(off, cursor, csr, y2, agg2);
    finish_kernel<<<dim3((N_NODES * CLS_F + 255) / 256), blk, 0, stream>>>(agg2, dinv, b2, out);
}

// Round 4
// 480.787 us; speedup vs baseline: 1.6276x; 1.1692x over previous
//
#include <hip/hip_runtime.h>

#define N_NODES 100000
#define N_EDGES 1600000
#define IN_F 128
#define HID_F 64
#define CLS_F 32

// ---------------------------------------------------------------------------
// CSR build: cnt (in-degree histogram) -> wave-scan segment alloc -> fill.
// ---------------------------------------------------------------------------

__global__ __launch_bounds__(256) void init_kernel(int* __restrict__ cnt,
                                                   int* __restrict__ counter) {
    int n = blockIdx.x * 256 + threadIdx.x;
    if (n < N_NODES) cnt[n] = 0;
    if (n == 0) *counter = 0;
}

__global__ __launch_bounds__(256) void count_kernel(const int* __restrict__ dst,
                                                    int* __restrict__ cnt) {
    int e = blockIdx.x * 256 + threadIdx.x;
    if (e < N_EDGES) atomicAdd(&cnt[dst[e]], 1);
}

__global__ __launch_bounds__(256) void alloc_kernel(const int* __restrict__ cnt,
                                                    int* __restrict__ off,
                                                    int* __restrict__ cursor,
                                                    float* __restrict__ dinv,
                                                    int* __restrict__ counter) {
    int n = blockIdx.x * 256 + threadIdx.x;
    int lane = threadIdx.x & 63;
    int c = (n < N_NODES) ? cnt[n] : 0;
    if (n < N_NODES) dinv[n] = rsqrtf((float)(c + 1));
    int s = c;
#pragma unroll
    for (int d = 1; d < 64; d <<= 1) {
        int t = __shfl_up(s, d);
        if (lane >= d) s += t;
    }
    int total = __shfl(s, 63);
    int base = 0;
    if (lane == 63) base = atomicAdd(counter, total);
    base = __shfl(base, 63);
    if (n < N_NODES) {
        int o = base + s - c;
        off[n] = o;
        cursor[n] = o;
    }
}

__global__ __launch_bounds__(256) void fill_kernel(const int* __restrict__ src,
                                                   const int* __restrict__ dst,
                                                   int* __restrict__ cursor,
                                                   int* __restrict__ csr) {
    int e = blockIdx.x * 256 + threadIdx.x;
    if (e >= N_EDGES) return;
    int p = atomicAdd(&cursor[dst[e]], 1);
    csr[p] = src[e];
}

// ---------------------------------------------------------------------------
// layer 1 GEMM: y1 = (x @ W1) * dinv.  BM=128 nodes/block, N=64 full,
// K chunked by 32 with transposed x-tile in LDS. 8x4 micro-tile per thread.
// ---------------------------------------------------------------------------
#define BM1 128
__global__ __launch_bounds__(256) void xw1_kernel(const float* __restrict__ x,
                                                  const float* __restrict__ W1,
                                                  const float* __restrict__ dinv,
                                                  float* __restrict__ y1) {
    __shared__ float Ws[IN_F * HID_F];     // 32 KB
    __shared__ float xs[32][BM1 + 4];      // ~16.9 KB, stride 132 (16B-aligned rows)

    const float4* w4 = (const float4*)W1;
    float4* ws4 = (float4*)Ws;
    for (int i = threadIdx.x; i < IN_F * HID_F / 4; i += 256) ws4[i] = w4[i];

    int tid = threadIdx.x;
    int tx = tid & 15, ty = tid >> 4;
    int c0 = tx * 4, r0 = ty * 8;
    int nodeBase = blockIdx.x * BM1;

    float acc[8][4];
#pragma unroll
    for (int i = 0; i < 8; i++)
#pragma unroll
        for (int j = 0; j < 4; j++) acc[i][j] = 0.f;

    int sNode = tid >> 3;        // 0..31
    int sK4 = (tid & 7) * 4;     // 0,4,...,28

    for (int kc = 0; kc < IN_F; kc += 32) {
        __syncthreads();
#pragma unroll
        for (int p = 0; p < 4; p++) {
            int nl = p * 32 + sNode;
            int n = nodeBase + nl;
            float4 v = make_float4(0.f, 0.f, 0.f, 0.f);
            if (n < N_NODES) v = *(const float4*)(x + (size_t)n * IN_F + kc + sK4);
            xs[sK4 + 0][nl] = v.x;
            xs[sK4 + 1][nl] = v.y;
            xs[sK4 + 2][nl] = v.z;
            xs[sK4 + 3][nl] = v.w;
        }
        __syncthreads();
#pragma unroll
        for (int k = 0; k < 32; k++) {
            float4 wv = *(const float4*)(Ws + (kc + k) * HID_F + c0);
            float4 xa = *(const float4*)(&xs[k][r0]);
            float4 xb = *(const float4*)(&xs[k][r0 + 4]);
            float xr[8] = {xa.x, xa.y, xa.z, xa.w, xb.x, xb.y, xb.z, xb.w};
            float wr[4] = {wv.x, wv.y, wv.z, wv.w};
#pragma unroll
            for (int i = 0; i < 8; i++)
#pragma unroll
                for (int j = 0; j < 4; j++) acc[i][j] += xr[i] * wr[j];
        }
    }

#pragma unroll
    for (int i = 0; i < 8; i++) {
        int n = nodeBase + r0 + i;
        if (n < N_NODES) {
            float dv = dinv[n];
            *(float4*)(y1 + (size_t)n * HID_F + c0) =
                make_float4(acc[i][0] * dv, acc[i][1] * dv, acc[i][2] * dv, acc[i][3] * dv);
        }
    }
}

// --- gather layer 1: one wave per node, lane = feature --------------------
__global__ __launch_bounds__(256) void gather1_kernel(const int* __restrict__ off,
                                                      const int* __restrict__ endp,
                                                      const int* __restrict__ csr,
                                                      const float* __restrict__ y1,
                                                      float* __restrict__ agg1) {
    int node = (blockIdx.x * 256 + threadIdx.x) >> 6;
    int lane = threadIdx.x & 63;
    if (node >= N_NODES) return;
    int start = off[node], end = endp[node];

    float acc = y1[(size_t)node * HID_F + lane];   // self loop
    for (int j = start; j < end; j += 64) {
        int m = min(64, end - j);
        int nbr = (lane < m) ? csr[j + lane] : 0;
        int i = 0;
        for (; i + 4 <= m; i += 4) {
            int s0 = __shfl(nbr, i), s1 = __shfl(nbr, i + 1);
            int s2 = __shfl(nbr, i + 2), s3 = __shfl(nbr, i + 3);
            float v0 = y1[(size_t)s0 * HID_F + lane];
            float v1 = y1[(size_t)s1 * HID_F + lane];
            float v2 = y1[(size_t)s2 * HID_F + lane];
            float v3 = y1[(size_t)s3 * HID_F + lane];
            acc += (v0 + v1) + (v2 + v3);
        }
        for (; i < m; i++) {
            int s = __shfl(nbr, i);
            acc += y1[(size_t)s * HID_F + lane];
        }
    }
    agg1[(size_t)node * HID_F + lane] = acc;
}

// ---------------------------------------------------------------------------
// layer 2 GEMM: y2 = (relu(agg1*dinv + b1) @ W2) * dinv.  BM=128, K=64 full,
// N=32. relu+bias+dinv fused into staging. 4x4 micro-tile per thread.
// ---------------------------------------------------------------------------
#define BM2 128
__global__ __launch_bounds__(256) void layer2_kernel(const float* __restrict__ agg1,
                                                     const float* __restrict__ dinv,
                                                     const float* __restrict__ W2,
                                                     const float* __restrict__ b1,
                                                     float* __restrict__ y2) {
    __shared__ float Ws[HID_F * CLS_F];    // 8 KB
    __shared__ float hs[HID_F][BM2 + 4];   // ~33.8 KB, stride 132

    const float4* w4 = (const float4*)W2;
    float4* ws4 = (float4*)Ws;
    for (int i = threadIdx.x; i < HID_F * CLS_F / 4; i += 256) ws4[i] = w4[i];

    int tid = threadIdx.x;
    int nodeBase = blockIdx.x * BM2;

    // staging: 16 threads per row (16 float4 = 64 floats), 16 rows per pass, 8 passes
    int sNode = tid >> 4;        // 0..15
    int sK4 = (tid & 15) * 4;    // 0..60
    float4 bv = *(const float4*)(b1 + sK4);

#pragma unroll
    for (int p = 0; p < 8; p++) {
        int nl = p * 16 + sNode;
        int n = nodeBase + nl;
        float4 v = make_float4(0.f, 0.f, 0.f, 0.f);
        float dv = 0.f;
        if (n < N_NODES) {
            v = *(const float4*)(agg1 + (size_t)n * HID_F + sK4);
            dv = dinv[n];
        }
        hs[sK4 + 0][nl] = fmaxf(v.x * dv + bv.x, 0.f);
        hs[sK4 + 1][nl] = fmaxf(v.y * dv + bv.y, 0.f);
        hs[sK4 + 2][nl] = fmaxf(v.z * dv + bv.z, 0.f);
        hs[sK4 + 3][nl] = fmaxf(v.w * dv + bv.w, 0.f);
    }
    __syncthreads();

    int tx = tid & 7, ty = tid >> 3;
    int c0 = tx * 4, r0 = ty * 4;

    float acc[4][4];
#pragma unroll
    for (int i = 0; i < 4; i++)
#pragma unroll
        for (int j = 0; j < 4; j++) acc[i][j] = 0.f;

#pragma unroll
    for (int k = 0; k < HID_F; k++) {
        float4 wv = *(const float4*)(Ws + k * CLS_F + c0);
        float4 xa = *(const float4*)(&hs[k][r0]);
        float xr[4] = {xa.x, xa.y, xa.z, xa.w};
        float wr[4] = {wv.x, wv.y, wv.z, wv.w};
#pragma unroll
        for (int i = 0; i < 4; i++)
#pragma unroll
            for (int j = 0; j < 4; j++) acc[i][j] += xr[i] * wr[j];
    }

#pragma unroll
    for (int i = 0; i < 4; i++) {
        int n = nodeBase + r0 + i;
        if (n < N_NODES) {
            float dv = dinv[n];
            *(float4*)(y2 + (size_t)n * CLS_F + c0) =
                make_float4(acc[i][0] * dv, acc[i][1] * dv, acc[i][2] * dv, acc[i][3] * dv);
        }
    }
}

// --- gather layer 2: half-wave (32 lanes) per node ------------------------
__global__ __launch_bounds__(256) void gather2_kernel(const int* __restrict__ off,
                                                      const int* __restrict__ endp,
                                                      const int* __restrict__ csr,
                                                      const float* __restrict__ y2,
                                                      float* __restrict__ agg2) {
    int node = (blockIdx.x * 256 + threadIdx.x) >> 5;
    int lane = threadIdx.x & 31;
    if (node >= N_NODES) return;
    int start = off[node], end = endp[node];

    float acc = y2[(size_t)node * CLS_F + lane];   // self loop
    for (int j = start; j < end; j += 32) {
        int m = min(32, end - j);
        int nbr = (lane < m) ? csr[j + lane] : 0;
        int i = 0;
        for (; i + 4 <= m; i += 4) {
            int s0 = __shfl(nbr, i, 32), s1 = __shfl(nbr, i + 1, 32);
            int s2 = __shfl(nbr, i + 2, 32), s3 = __shfl(nbr, i + 3, 32);
            float v0 = y2[(size_t)s0 * CLS_F + lane];
            float v1 = y2[(size_t)s1 * CLS_F + lane];
            float v2 = y2[(size_t)s2 * CLS_F + lane];
            float v3 = y2[(size_t)s3 * CLS_F + lane];
            acc += (v0 + v1) + (v2 + v3);
        }
        for (; i < m; i++) {
            int s = __shfl(nbr, i, 32);
            acc += y2[(size_t)s * CLS_F + lane];
        }
    }
    agg2[(size_t)node * CLS_F + lane] = acc;
}

// --- epilogue: out = agg2*dinv + b2 ---------------------------------------
__global__ __launch_bounds__(256) void finish_kernel(const float* __restrict__ agg2,
                                                     const float* __restrict__ dinv,
                                                     const float* __restrict__ b2,
                                                     float* __restrict__ out) {
    int gid = blockIdx.x * 256 + threadIdx.x;
    if (gid >= N_NODES * CLS_F) return;
    int n = gid >> 5;
    int c = gid & 31;
    out[gid] = agg2[gid] * dinv[n] + b2[c];
}

extern "C" void kernel_launch(void* const* d_in, const int* in_sizes, int n_in,
                              void* d_out, int out_size, void* d_ws, size_t ws_size,
                              hipStream_t stream) {
    const float* x  = (const float*)d_in[0];
    const int*   ei = (const int*)d_in[1];
    // d_in[2] = edge_attr, unused by GCNConv
    const float* W1 = (const float*)d_in[3];
    const float* b1 = (const float*)d_in[4];
    const float* W2 = (const float*)d_in[5];
    const float* b2 = (const float*)d_in[6];
    float* out = (float*)d_out;

    const int* src = ei;
    const int* dst = ei + N_EDGES;

    char* ws = (char*)d_ws;
    size_t npad = ((size_t)N_NODES * 4 + 255) / 256 * 256;
    float* dinv   = (float*)ws;
    int*   cnt    = (int*)(ws + npad);
    int*   off    = (int*)(ws + 2 * npad);
    int*   cursor = (int*)(ws + 3 * npad);
    int*   counter= (int*)(ws + 4 * npad);
    int*   csr    = (int*)(ws + 4 * npad + 256);
    float* y1     = (float*)(ws + 4 * npad + 256 + (size_t)N_EDGES * 4);
    float* agg1   = y1 + (size_t)N_NODES * HID_F;
    float* y2     = y1;                                // y1 dead after gather1
    float* agg2   = y1 + (size_t)N_NODES * CLS_F;

    dim3 blk(256);
    int nb_nodes = (N_NODES + 255) / 256;
    int nb_edges = (N_EDGES + 255) / 256;
    init_kernel <<<dim3(nb_nodes), blk, 0, stream>>>(cnt, counter);
    count_kernel<<<dim3(nb_edges), blk, 0, stream>>>(dst, cnt);
    alloc_kernel<<<dim3(nb_nodes), blk, 0, stream>>>(cnt, off, cursor, dinv, counter);
    fill_kernel <<<dim3(nb_edges), blk, 0, stream>>>(src, dst, cursor, csr);
    xw1_kernel  <<<dim3((N_NODES + BM1 - 1) / BM1), blk, 0, stream>>>(x, W1, dinv, y1);
    gather1_kernel<<<dim3((N_NODES * 64 + 255) / 256), blk, 0, stream>>>(off, cursor, csr, y1, agg1);
    layer2_kernel<<<dim3((N_NODES + BM2 - 1) / BM2), blk, 0, stream>>>(agg1, dinv, W2, b1, y2);
    gather2_kernel<<<dim3((N_NODES * 32 + 255) / 256), blk, 0, stream>>>(off, cursor, csr, y2, agg2);
    finish_kernel<<<dim3((N_NODES * CLS_F + 255) / 256), blk, 0, stream>>>(agg2, dinv, b2, out);
}

// Round 5
// 423.664 us; speedup vs baseline: 1.8470x; 1.1348x over previous
//
#include <hip/hip_runtime.h>

#define N_NODES 100000
#define N_EDGES 1600000
#define IN_F 128
#define HID_F 64
#define CLS_F 32
#define NB_SCAN ((N_NODES + 255) / 256)   // 391
#define NGRP 8
#define GRP_SZ (N_NODES / NGRP)           // 12500

// ---------------------------------------------------------------------------
// CSR build, deterministic offsets:
//   cnt histogram (XCD-grouped atomics) -> block scan -> top scan -> add base
//   -> fill (XCD-grouped by dst range; csr region per group is contiguous)
// ---------------------------------------------------------------------------

__global__ __launch_bounds__(256) void init_kernel(int* __restrict__ cnt) {
    int n = blockIdx.x * 256 + threadIdx.x;
    if (n < N_NODES) cnt[n] = 0;
}

// group g (blockIdx%8 -> XCD heuristic) handles dst in [g*GRP_SZ,(g+1)*GRP_SZ)
__global__ __launch_bounds__(256) void count_kernel(const int* __restrict__ dst,
                                                    int* __restrict__ cnt) {
    int g = blockIdx.x & (NGRP - 1);
    int blk = blockIdx.x >> 3;
    int lo = g * GRP_SZ, hi = lo + GRP_SZ;
    int stride = (gridDim.x >> 3) * 256;
    for (int e = blk * 256 + threadIdx.x; e < N_EDGES; e += stride) {
        int d = dst[e];
        if (d >= lo && d < hi) atomicAdd(&cnt[d], 1);
    }
}

// per-256-block exclusive scan of cnt -> off (local), block total -> bsum,
// dinv = rsqrt(cnt+1)
__global__ __launch_bounds__(256) void scan_block_kernel(const int* __restrict__ cnt,
                                                         int* __restrict__ off,
                                                         int* __restrict__ bsum,
                                                         float* __restrict__ dinv) {
    __shared__ int wt[4];
    int t = threadIdx.x;
    int n = blockIdx.x * 256 + t;
    int lane = t & 63, w = t >> 6;
    int c = (n < N_NODES) ? cnt[n] : 0;
    if (n < N_NODES) dinv[n] = rsqrtf((float)(c + 1));
    int s = c;
#pragma unroll
    for (int d = 1; d < 64; d <<= 1) {
        int t2 = __shfl_up(s, d);
        if (lane >= d) s += t2;
    }
    if (lane == 63) wt[w] = s;
    __syncthreads();
    int base = 0;
    for (int i = 0; i < w; i++) base += wt[i];
    if (n < N_NODES) off[n] = base + s - c;
    if (t == 255) bsum[blockIdx.x] = wt[0] + wt[1] + wt[2] + wt[3];
}

__global__ void scan_top_kernel(const int* __restrict__ bsum,
                                int* __restrict__ bbase) {
    if (threadIdx.x == 0 && blockIdx.x == 0) {
        int acc = 0;
        for (int i = 0; i < NB_SCAN; i++) { bbase[i] = acc; acc += bsum[i]; }
    }
}

__global__ __launch_bounds__(256) void add_base_kernel(int* __restrict__ off,
                                                       const int* __restrict__ bbase,
                                                       int* __restrict__ cursor) {
    int n = blockIdx.x * 256 + threadIdx.x;
    if (n < N_NODES) {
        int o = off[n] + bbase[n >> 8];
        off[n] = o;
        cursor[n] = o;
    }
}

// XCD-grouped fill: group g writes only csr[off[g*GRP_SZ] .. ) contiguous
__global__ __launch_bounds__(256) void fill_kernel(const int* __restrict__ src,
                                                   const int* __restrict__ dst,
                                                   int* __restrict__ cursor,
                                                   int* __restrict__ csr) {
    int g = blockIdx.x & (NGRP - 1);
    int blk = blockIdx.x >> 3;
    int lo = g * GRP_SZ, hi = lo + GRP_SZ;
    int stride = (gridDim.x >> 3) * 256;
    for (int e = blk * 256 + threadIdx.x; e < N_EDGES; e += stride) {
        int d = dst[e];
        if (d >= lo && d < hi) {
            int p = atomicAdd(&cursor[d], 1);
            csr[p] = src[e];
        }
    }
}

// ---------------------------------------------------------------------------
// layer 1 GEMM: y1 = (x @ W1) * dinv.  BM=128 nodes/block, 8x4 micro-tile.
// ---------------------------------------------------------------------------
#define BM1 128
__global__ __launch_bounds__(256) void xw1_kernel(const float* __restrict__ x,
                                                  const float* __restrict__ W1,
                                                  const float* __restrict__ dinv,
                                                  float* __restrict__ y1) {
    __shared__ float Ws[IN_F * HID_F];     // 32 KB
    __shared__ float xs[32][BM1 + 4];      // ~16.9 KB

    const float4* w4 = (const float4*)W1;
    float4* ws4 = (float4*)Ws;
    for (int i = threadIdx.x; i < IN_F * HID_F / 4; i += 256) ws4[i] = w4[i];

    int tid = threadIdx.x;
    int tx = tid & 15, ty = tid >> 4;
    int c0 = tx * 4, r0 = ty * 8;
    int nodeBase = blockIdx.x * BM1;

    float acc[8][4];
#pragma unroll
    for (int i = 0; i < 8; i++)
#pragma unroll
        for (int j = 0; j < 4; j++) acc[i][j] = 0.f;

    int sNode = tid >> 3;        // 0..31
    int sK4 = (tid & 7) * 4;     // 0,4,...,28

    for (int kc = 0; kc < IN_F; kc += 32) {
        __syncthreads();
#pragma unroll
        for (int p = 0; p < 4; p++) {
            int nl = p * 32 + sNode;
            int n = nodeBase + nl;
            float4 v = make_float4(0.f, 0.f, 0.f, 0.f);
            if (n < N_NODES) v = *(const float4*)(x + (size_t)n * IN_F + kc + sK4);
            xs[sK4 + 0][nl] = v.x;
            xs[sK4 + 1][nl] = v.y;
            xs[sK4 + 2][nl] = v.z;
            xs[sK4 + 3][nl] = v.w;
        }
        __syncthreads();
#pragma unroll
        for (int k = 0; k < 32; k++) {
            float4 wv = *(const float4*)(Ws + (kc + k) * HID_F + c0);
            float4 xa = *(const float4*)(&xs[k][r0]);
            float4 xb = *(const float4*)(&xs[k][r0 + 4]);
            float xr[8] = {xa.x, xa.y, xa.z, xa.w, xb.x, xb.y, xb.z, xb.w};
            float wr[4] = {wv.x, wv.y, wv.z, wv.w};
#pragma unroll
            for (int i = 0; i < 8; i++)
#pragma unroll
                for (int j = 0; j < 4; j++) acc[i][j] += xr[i] * wr[j];
        }
    }

#pragma unroll
    for (int i = 0; i < 8; i++) {
        int n = nodeBase + r0 + i;
        if (n < N_NODES) {
            float dv = dinv[n];
            *(float4*)(y1 + (size_t)n * HID_F + c0) =
                make_float4(acc[i][0] * dv, acc[i][1] * dv, acc[i][2] * dv, acc[i][3] * dv);
        }
    }
}

// --- gather layer 1: one wave per node, lane = feature --------------------
__global__ __launch_bounds__(256) void gather1_kernel(const int* __restrict__ off,
                                                      const int* __restrict__ endp,
                                                      const int* __restrict__ csr,
                                                      const float* __restrict__ y1,
                                                      float* __restrict__ agg1) {
    int node = (blockIdx.x * 256 + threadIdx.x) >> 6;
    int lane = threadIdx.x & 63;
    if (node >= N_NODES) return;
    int start = off[node], end = endp[node];

    float acc = y1[(size_t)node * HID_F + lane];   // self loop
    for (int j = start; j < end; j += 64) {
        int m = min(64, end - j);
        int nbr = (lane < m) ? csr[j + lane] : 0;
        int i = 0;
        for (; i + 4 <= m; i += 4) {
            int s0 = __shfl(nbr, i), s1 = __shfl(nbr, i + 1);
            int s2 = __shfl(nbr, i + 2), s3 = __shfl(nbr, i + 3);
            float v0 = y1[(size_t)s0 * HID_F + lane];
            float v1 = y1[(size_t)s1 * HID_F + lane];
            float v2 = y1[(size_t)s2 * HID_F + lane];
            float v3 = y1[(size_t)s3 * HID_F + lane];
            acc += (v0 + v1) + (v2 + v3);
        }
        for (; i < m; i++) {
            int s = __shfl(nbr, i);
            acc += y1[(size_t)s * HID_F + lane];
        }
    }
    agg1[(size_t)node * HID_F + lane] = acc;
}

// ---------------------------------------------------------------------------
// layer 2 GEMM: y2 = (relu(agg1*dinv + b1) @ W2) * dinv.
// ---------------------------------------------------------------------------
#define BM2 128
__global__ __launch_bounds__(256) void layer2_kernel(const float* __restrict__ agg1,
                                                     const float* __restrict__ dinv,
                                                     const float* __restrict__ W2,
                                                     const float* __restrict__ b1,
                                                     float* __restrict__ y2) {
    __shared__ float Ws[HID_F * CLS_F];    // 8 KB
    __shared__ float hs[HID_F][BM2 + 4];   // ~33.8 KB

    const float4* w4 = (const float4*)W2;
    float4* ws4 = (float4*)Ws;
    for (int i = threadIdx.x; i < HID_F * CLS_F / 4; i += 256) ws4[i] = w4[i];

    int tid = threadIdx.x;
    int nodeBase = blockIdx.x * BM2;

    int sNode = tid >> 4;        // 0..15
    int sK4 = (tid & 15) * 4;    // 0..60
    float4 bv = *(const float4*)(b1 + sK4);

#pragma unroll
    for (int p = 0; p < 8; p++) {
        int nl = p * 16 + sNode;
        int n = nodeBase + nl;
        float4 v = make_float4(0.f, 0.f, 0.f, 0.f);
        float dv = 0.f;
        if (n < N_NODES) {
            v = *(const float4*)(agg1 + (size_t)n * HID_F + sK4);
            dv = dinv[n];
        }
        hs[sK4 + 0][nl] = fmaxf(v.x * dv + bv.x, 0.f);
        hs[sK4 + 1][nl] = fmaxf(v.y * dv + bv.y, 0.f);
        hs[sK4 + 2][nl] = fmaxf(v.z * dv + bv.z, 0.f);
        hs[sK4 + 3][nl] = fmaxf(v.w * dv + bv.w, 0.f);
    }
    __syncthreads();

    int tx = tid & 7, ty = tid >> 3;
    int c0 = tx * 4, r0 = ty * 4;

    float acc[4][4];
#pragma unroll
    for (int i = 0; i < 4; i++)
#pragma unroll
        for (int j = 0; j < 4; j++) acc[i][j] = 0.f;

#pragma unroll
    for (int k = 0; k < HID_F; k++) {
        float4 wv = *(const float4*)(Ws + k * CLS_F + c0);
        float4 xa = *(const float4*)(&hs[k][r0]);
        float xr[4] = {xa.x, xa.y, xa.z, xa.w};
        float wr[4] = {wv.x, wv.y, wv.z, wv.w};
#pragma unroll
        for (int i = 0; i < 4; i++)
#pragma unroll
            for (int j = 0; j < 4; j++) acc[i][j] += xr[i] * wr[j];
    }

#pragma unroll
    for (int i = 0; i < 4; i++) {
        int n = nodeBase + r0 + i;
        if (n < N_NODES) {
            float dv = dinv[n];
            *(float4*)(y2 + (size_t)n * CLS_F + c0) =
                make_float4(acc[i][0] * dv, acc[i][1] * dv, acc[i][2] * dv, acc[i][3] * dv);
        }
    }
}

// --- gather layer 2: half-wave (32 lanes) per node ------------------------
__global__ __launch_bounds__(256) void gather2_kernel(const int* __restrict__ off,
                                                      const int* __restrict__ endp,
                                                      const int* __restrict__ csr,
                                                      const float* __restrict__ y2,
                                                      float* __restrict__ agg2) {
    int node = (blockIdx.x * 256 + threadIdx.x) >> 5;
    int lane = threadIdx.x & 31;
    if (node >= N_NODES) return;
    int start = off[node], end = endp[node];

    float acc = y2[(size_t)node * CLS_F + lane];   // self loop
    for (int j = start; j < end; j += 32) {
        int m = min(32, end - j);
        int nbr = (lane < m) ? csr[j + lane] : 0;
        int i = 0;
        for (; i + 4 <= m; i += 4) {
            int s0 = __shfl(nbr, i, 32), s1 = __shfl(nbr, i + 1, 32);
            int s2 = __shfl(nbr, i + 2, 32), s3 = __shfl(nbr, i + 3, 32);
            float v0 = y2[(size_t)s0 * CLS_F + lane];
            float v1 = y2[(size_t)s1 * CLS_F + lane];
            float v2 = y2[(size_t)s2 * CLS_F + lane];
            float v3 = y2[(size_t)s3 * CLS_F + lane];
            acc += (v0 + v1) + (v2 + v3);
        }
        for (; i < m; i++) {
            int s = __shfl(nbr, i, 32);
            acc += y2[(size_t)s * CLS_F + lane];
        }
    }
    agg2[(size_t)node * CLS_F + lane] = acc;
}

// --- epilogue: out = agg2*dinv + b2 ---------------------------------------
__global__ __launch_bounds__(256) void finish_kernel(const float* __restrict__ agg2,
                                                     const float* __restrict__ dinv,
                                                     const float* __restrict__ b2,
                                                     float* __restrict__ out) {
    int gid = blockIdx.x * 256 + threadIdx.x;
    if (gid >= N_NODES * CLS_F) return;
    int n = gid >> 5;
    int c = gid & 31;
    out[gid] = agg2[gid] * dinv[n] + b2[c];
}

extern "C" void kernel_launch(void* const* d_in, const int* in_sizes, int n_in,
                              void* d_out, int out_size, void* d_ws, size_t ws_size,
                              hipStream_t stream) {
    const float* x  = (const float*)d_in[0];
    const int*   ei = (const int*)d_in[1];
    // d_in[2] = edge_attr, unused by GCNConv
    const float* W1 = (const float*)d_in[3];
    const float* b1 = (const float*)d_in[4];
    const float* W2 = (const float*)d_in[5];
    const float* b2 = (const float*)d_in[6];
    float* out = (float*)d_out;

    const int* src = ei;
    const int* dst = ei + N_EDGES;

    char* ws = (char*)d_ws;
    size_t npad = ((size_t)N_NODES * 4 + 255) / 256 * 256;
    float* dinv   = (float*)ws;
    int*   cnt    = (int*)(ws + npad);
    int*   off    = (int*)(ws + 2 * npad);
    int*   cursor = (int*)(ws + 3 * npad);
    int*   bsum   = (int*)(ws + 4 * npad);            // NB_SCAN ints
    int*   bbase  = bsum + 512;                       // NB_SCAN ints
    int*   csr    = (int*)(ws + 4 * npad + 4096);
    float* y1     = (float*)(ws + 4 * npad + 4096 + (size_t)N_EDGES * 4);
    float* agg1   = y1 + (size_t)N_NODES * HID_F;
    float* y2     = y1;                                // y1 dead after gather1
    float* agg2   = y1 + (size_t)N_NODES * CLS_F;

    dim3 blk(256);
    int nb_nodes = (N_NODES + 255) / 256;
    init_kernel <<<dim3(nb_nodes), blk, 0, stream>>>(cnt);
    count_kernel<<<dim3(1024), blk, 0, stream>>>(dst, cnt);
    scan_block_kernel<<<dim3(NB_SCAN), blk, 0, stream>>>(cnt, off, bsum, dinv);
    scan_top_kernel<<<dim3(1), blk, 0, stream>>>(bsum, bbase);
    add_base_kernel<<<dim3(nb_nodes), blk, 0, stream>>>(off, bbase, cursor);
    fill_kernel <<<dim3(2048), blk, 0, stream>>>(src, dst, cursor, csr);
    xw1_kernel  <<<dim3((N_NODES + BM1 - 1) / BM1), blk, 0, stream>>>(x, W1, dinv, y1);
    gather1_kernel<<<dim3((N_NODES * 64 + 255) / 256), blk, 0, stream>>>(off, cursor, csr, y1, agg1);
    layer2_kernel<<<dim3((N_NODES + BM2 - 1) / BM2), blk, 0, stream>>>(agg1, dinv, W2, b1, y2);
    gather2_kernel<<<dim3((N_NODES * 32 + 255) / 256), blk, 0, stream>>>(off, cursor, csr, y2, agg2);
    finish_kernel<<<dim3((N_NODES * CLS_F + 255) / 256), blk, 0, stream>>>(agg2, dinv, b2, out);
}